// Round 3
// baseline (632.338 us; speedup 1.0000x reference)
//
#include <hip/hip_runtime.h>
#include <stdint.h>

#define T_TOK 1024
#define H_DIM 1024
#define I_DIM 2816
#define E_NUM 8
#define KSPLIT 2
#define K2_STEPS (I_DIM / 64 / KSPLIT)   // 22 K-steps of 64 per split
#define MAXROWS 3072

typedef __attribute__((ext_vector_type(8)))  short bf16x8;
typedef __attribute__((ext_vector_type(16))) float f32x16;

struct Meta { int counts[E_NUM]; int tiles[E_NUM]; int offs[E_NUM]; };

__device__ __forceinline__ unsigned short f2b(float f) {
    unsigned u = __float_as_uint(f);
    u += 0x7fffu + ((u >> 16) & 1u);   // round-to-nearest-even
    return (unsigned short)(u >> 16);
}

__device__ __forceinline__ uint4 pack8(const float4 a, const float4 b) {
    union { unsigned short us[8]; uint4 v; } u;
    u.us[0] = f2b(a.x); u.us[1] = f2b(a.y); u.us[2] = f2b(a.z); u.us[3] = f2b(a.w);
    u.us[4] = f2b(b.x); u.us[5] = f2b(b.y); u.us[6] = f2b(b.z); u.us[7] = f2b(b.w);
    return u.v;
}

#define WAIT_ALL() asm volatile("s_waitcnt vmcnt(0) lgkmcnt(0)" ::: "memory")
#define BAR() __builtin_amdgcn_s_barrier()
#define SCHED_FENCE() __builtin_amdgcn_sched_barrier(0)

// async global->LDS, 16B per lane, linear dest (wave base + lane*16)
__device__ __forceinline__ void gload16(const unsigned short* src, unsigned short* ldsdst) {
    __builtin_amdgcn_global_load_lds(
        (const __attribute__((address_space(1))) unsigned int*)src,
        (__attribute__((address_space(3))) unsigned int*)ldsdst, 16, 0, 0);
}

// ---------------- routing ----------------
__global__ void route_kernel(const float* __restrict__ logits,
                             int* __restrict__ tok,
                             int4* __restrict__ comb,
                             Meta* __restrict__ meta) {
    __shared__ int cnt[E_NUM];
    __shared__ int soffs[E_NUM];
    const int tid = threadIdx.x;   // == token id, blockDim=1024
    if (tid < E_NUM) cnt[tid] = 0;
    for (int j = tid; j < E_NUM * T_TOK; j += 1024) tok[j] = 0;
    __syncthreads();

    float p[E_NUM];
    const float* lrow = logits + tid * E_NUM;
    float m = -1e30f;
    #pragma unroll
    for (int e = 0; e < E_NUM; ++e) { p[e] = lrow[e]; m = fmaxf(m, p[e]); }
    #pragma unroll
    for (int e = 0; e < E_NUM; ++e) p[e] = __expf(p[e] - m);
    int e0 = 0; float v0 = p[0];
    #pragma unroll
    for (int e = 1; e < E_NUM; ++e) if (p[e] > v0) { v0 = p[e]; e0 = e; }
    int e1 = -1; float v1 = -1.f;
    #pragma unroll
    for (int e = 0; e < E_NUM; ++e) if (e != e0 && p[e] > v1) { v1 = p[e]; e1 = e; }
    const float inv = 1.f / (v0 + v1);
    const float g0 = v0 * inv, g1 = v1 * inv;

    const int p0 = atomicAdd(&cnt[e0], 1);
    const int p1 = atomicAdd(&cnt[e1], 1);
    tok[e0 * T_TOK + p0] = tid;
    tok[e1 * T_TOK + p1] = tid;
    __syncthreads();
    if (tid == 0) {
        int off = 0;
        for (int e = 0; e < E_NUM; ++e) {
            const int c = cnt[e];
            const int t = (c + 127) >> 7;
            meta->counts[e] = c; meta->tiles[e] = t; meta->offs[e] = off;
            soffs[e] = off;
            off += t * 128;
        }
    }
    __syncthreads();
    comb[tid] = make_int4(soffs[e0] + p0, soffs[e1] + p1,
                          __float_as_int(g0), __float_as_int(g1));
}

// ---------------- x fp32 -> bf16 ----------------
__global__ void cvt_x_kernel(const float* __restrict__ x, unsigned short* __restrict__ xb) {
    const int i = blockIdx.x * blockDim.x + threadIdx.x;
    const float4 v = ((const float4*)x)[i];
    ushort4 o; o.x = f2b(v.x); o.y = f2b(v.y); o.z = f2b(v.z); o.w = f2b(v.w);
    ((ushort4*)xb)[i] = o;
}

// ---------------- GEMM1: act = silu(x@w1^T) * (x@w3^T) ----------------
// grid (mt=8, E, it=44), block 256 (4 waves). Tile 128(M)x64(N), BK=64, 32x32x16 MFMA.
// waves 0-1: w1; waves 2-3: w3 (same 128x64 tile); silu pairing via LDS exchange.
// A: global_load_lds double-buffered, XOR-chunk-swizzled via pre-swizzled source.
// B: reg-staged fp32->bf16, padded stride 68 shorts (conflict-free reads).
__launch_bounds__(256, 3)
__global__ void gemm1_kernel(const unsigned short* __restrict__ xb,
                             const float* __restrict__ w1,
                             const float* __restrict__ w3,
                             const int* __restrict__ tok,
                             const Meta* __restrict__ meta,
                             unsigned short* __restrict__ act) {
    const int mt = blockIdx.x;
    const int e  = blockIdx.y;
    const int it = blockIdx.z;
    if (mt >= meta->tiles[e]) return;
    const int tid = threadIdx.x;

    __shared__ __align__(16) unsigned short As[2][128 * 64];   // 32 KB (also epilogue overlay)
    __shared__ __align__(16) unsigned short B1s[64 * 68];      // 8.5 KB padded
    __shared__ __align__(16) unsigned short B3s[64 * 68];

    const int wave = tid >> 6, lane = tid & 63;
    const int l8 = lane >> 3, c8 = lane & 7;

    // ---- A DMA setup: 4 issues/wave, rows (wave*4+i)*8 + l8, pre-swizzled source col ----
    const unsigned short* apg[4];
    #pragma unroll
    for (int i = 0; i < 4; ++i) {
        const int R = (wave * 4 + i) * 8 + l8;
        const int t = tok[e * T_TOK + mt * 128 + R];
        apg[i] = xb + (size_t)t * H_DIM + (c8 ^ (R & 7)) * 8;
    }

    // ---- B staging: row = tid>>2 (0..63), quarter = tid&3 -> 16 floats each matrix ----
    const int brow = tid >> 2, bq = tid & 3;
    const size_t woff = (size_t)e * I_DIM * H_DIM + (size_t)(it * 64 + brow) * H_DIM + bq * 16;
    const float* b1p = w1 + woff;
    const float* b3p = w3 + woff;
    const int bl = brow * 68 + bq * 16;

    // ---- wave/frag constants ----
    const int half = lane >> 5, l31 = lane & 31;
    const int pos = wave & 1, mat = wave >> 1;     // pos: M-half; mat: 0=w1, 1=w3
    const unsigned short* Bw = mat ? B3s : B1s;
    const int arow0 = (pos * 64 + l31) * 64;
    const int arow1 = (pos * 64 + 32 + l31) * 64;
    const int aswz  = l31 & 7;
    const int bfr0 = (l31) * 68 + half * 8;
    const int bfr1 = (32 + l31) * 68 + half * 8;

    f32x16 acc00 = {0}, acc01 = {0}, acc10 = {0}, acc11 = {0};

    float4 r0, r1, r2, r3, r4, r5, r6, r7;

#define G1_GLOAD(KS, B) do { \
        const int koff_ = (KS) * 64; \
        _Pragma("unroll") \
        for (int i = 0; i < 4; ++i) \
            gload16(apg[i] + koff_, &As[B][(wave * 4 + i) * 512 + lane * 8]); \
    } while (0)
    // note: hardware writes at ldsbase + lane*16B; passing per-lane ptr keeps semantics
    // identical because the builtin uses the wave-uniform base (lane offset is implicit).

#define G1_LOADB(KS) do { \
        const int koff_ = (KS) * 64; \
        r0 = *(const float4*)(b1p + koff_);      r1 = *(const float4*)(b1p + koff_ + 4); \
        r2 = *(const float4*)(b1p + koff_ + 8);  r3 = *(const float4*)(b1p + koff_ + 12); \
        r4 = *(const float4*)(b3p + koff_);      r5 = *(const float4*)(b3p + koff_ + 4); \
        r6 = *(const float4*)(b3p + koff_ + 8);  r7 = *(const float4*)(b3p + koff_ + 12); \
    } while (0)

#define G1_STOREB() do { \
        *(uint4*)&B1s[bl]     = pack8(r0, r1); \
        *(uint4*)&B1s[bl + 8] = pack8(r2, r3); \
        *(uint4*)&B3s[bl]     = pack8(r4, r5); \
        *(uint4*)&B3s[bl + 8] = pack8(r6, r7); \
    } while (0)

#define G1_COMPUTE(B) do { \
        _Pragma("unroll") \
        for (int kk = 0; kk < 4; ++kk) { \
            const int sc = ((kk * 2 + half) ^ aswz) * 8; \
            bf16x8 a0 = *(const bf16x8*)&As[B][arow0 + sc]; \
            bf16x8 a1 = *(const bf16x8*)&As[B][arow1 + sc]; \
            bf16x8 b0 = *(const bf16x8*)&Bw[bfr0 + kk * 16]; \
            bf16x8 b1 = *(const bf16x8*)&Bw[bfr1 + kk * 16]; \
            acc00 = __builtin_amdgcn_mfma_f32_32x32x16_bf16(a0, b0, acc00, 0, 0, 0); \
            acc01 = __builtin_amdgcn_mfma_f32_32x32x16_bf16(a0, b1, acc01, 0, 0, 0); \
            acc10 = __builtin_amdgcn_mfma_f32_32x32x16_bf16(a1, b0, acc10, 0, 0, 0); \
            acc11 = __builtin_amdgcn_mfma_f32_32x32x16_bf16(a1, b1, acc11, 0, 0, 0); \
        } \
    } while (0)

    // prologue: tile 0
    G1_GLOAD(0, 0);
    G1_LOADB(0);
    G1_STOREB();
    WAIT_ALL(); BAR();

    const int NK = H_DIM / 64;   // 16
    int cur = 0;
    for (int ks = 0; ks < NK; ++ks) {
        const bool pf = (ks + 1 < NK);
        if (pf) { G1_GLOAD(ks + 1, cur ^ 1); G1_LOADB(ks + 1); }
        G1_COMPUTE(cur);
        SCHED_FENCE();
        BAR();                       // all waves done reading B tile
        if (pf) G1_STOREB();
        WAIT_ALL(); BAR();           // B visible, A DMA landed
        cur ^= 1;
    }
#undef G1_GLOAD
#undef G1_LOADB
#undef G1_STOREB
#undef G1_COMPUTE

    // ---- epilogue: exchange acc3 via LDS overlay, fuse silu, store act ----
    float* ex = (float*)&As[0][0];   // 128x64 f32 = 32 KB
    const int opad = meta->offs[e];
    if (mat == 1) {
        #pragma unroll
        for (int mi = 0; mi < 2; ++mi)
            #pragma unroll
            for (int ni = 0; ni < 2; ++ni) {
                const f32x16 a = mi == 0 ? (ni == 0 ? acc00 : acc01) : (ni == 0 ? acc10 : acc11);
                #pragma unroll
                for (int r = 0; r < 16; ++r) {
                    const int frow = pos * 64 + mi * 32 + (r & 3) + 8 * (r >> 2) + 4 * half;
                    ex[frow * 64 + ni * 32 + l31] = a[r];
                }
            }
    }
    __syncthreads();
    if (mat == 0) {
        #pragma unroll
        for (int mi = 0; mi < 2; ++mi)
            #pragma unroll
            for (int ni = 0; ni < 2; ++ni) {
                const f32x16 a = mi == 0 ? (ni == 0 ? acc00 : acc01) : (ni == 0 ? acc10 : acc11);
                #pragma unroll
                for (int r = 0; r < 16; ++r) {
                    const int frow = pos * 64 + mi * 32 + (r & 3) + 8 * (r >> 2) + 4 * half;
                    const float v1 = a[r];
                    const float v3 = ex[frow * 64 + ni * 32 + l31];
                    const float s = v1 / (1.f + __expf(-v1)) * v3;
                    act[(size_t)(opad + mt * 128 + frow) * I_DIM + it * 64 + ni * 32 + l31] = f2b(s);
                }
            }
    }
}

// ---------------- GEMM2: ybuf[kb] = act @ w2^T (K-split halves), plain stores ----------------
// grid (x = kb*8+mt [16], E, it=16), block 256 (4 waves). Tile 128(M)x64(N), BK=64.
__launch_bounds__(256, 3)
__global__ void gemm2_kernel(const unsigned short* __restrict__ act,
                             const float* __restrict__ w2,
                             const Meta* __restrict__ meta,
                             float* __restrict__ ybuf) {
    const int mt = blockIdx.x & 7;
    const int kb = blockIdx.x >> 3;
    const int e  = blockIdx.y;
    const int it = blockIdx.z;
    if (mt >= meta->tiles[e]) return;
    const int tid = threadIdx.x;
    const int opad = meta->offs[e];
    const int kbase = kb * (K2_STEPS * 64);   // 0 or 1408

    __shared__ __align__(16) unsigned short As[2][128 * 64];   // 32 KB
    __shared__ __align__(16) unsigned short Bs[64 * 68];       // 8.5 KB

    const int wave = tid >> 6, lane = tid & 63;
    const int l8 = lane >> 3, c8 = lane & 7;

    const unsigned short* apg[4];
    #pragma unroll
    for (int i = 0; i < 4; ++i) {
        const int R = (wave * 4 + i) * 8 + l8;
        apg[i] = act + (size_t)(opad + mt * 128 + R) * I_DIM + kbase + (c8 ^ (R & 7)) * 8;
    }

    const int brow = tid >> 2, bq = tid & 3;
    const float* bp = w2 + (size_t)e * H_DIM * I_DIM + (size_t)(it * 64 + brow) * I_DIM + kbase + bq * 16;
    const int bl = brow * 68 + bq * 16;

    const int half = lane >> 5, l31 = lane & 31;
    const int wm = wave >> 1, wn = wave & 1;
    const int arow0 = (wm * 64 + l31) * 64;
    const int arow1 = (wm * 64 + 32 + l31) * 64;
    const int aswz  = l31 & 7;
    const int bfr = (wn * 32 + l31) * 68 + half * 8;

    f32x16 acc0 = {0}, acc1 = {0};
    float4 r0, r1, r2, r3;

#define G2_GLOAD(KS, B) do { \
        const int koff_ = (KS) * 64; \
        _Pragma("unroll") \
        for (int i = 0; i < 4; ++i) \
            gload16(apg[i] + koff_, &As[B][(wave * 4 + i) * 512 + lane * 8]); \
    } while (0)

#define G2_LOADB(KS) do { \
        const int koff_ = (KS) * 64; \
        r0 = *(const float4*)(bp + koff_);      r1 = *(const float4*)(bp + koff_ + 4); \
        r2 = *(const float4*)(bp + koff_ + 8);  r3 = *(const float4*)(bp + koff_ + 12); \
    } while (0)

#define G2_STOREB() do { \
        *(uint4*)&Bs[bl]     = pack8(r0, r1); \
        *(uint4*)&Bs[bl + 8] = pack8(r2, r3); \
    } while (0)

#define G2_COMPUTE(B) do { \
        _Pragma("unroll") \
        for (int kk = 0; kk < 4; ++kk) { \
            const int sc = ((kk * 2 + half) ^ aswz) * 8; \
            bf16x8 a0 = *(const bf16x8*)&As[B][arow0 + sc]; \
            bf16x8 a1 = *(const bf16x8*)&As[B][arow1 + sc]; \
            bf16x8 b0 = *(const bf16x8*)&Bs[bfr + kk * 16]; \
            acc0 = __builtin_amdgcn_mfma_f32_32x32x16_bf16(a0, b0, acc0, 0, 0, 0); \
            acc1 = __builtin_amdgcn_mfma_f32_32x32x16_bf16(a1, b0, acc1, 0, 0, 0); \
        } \
    } while (0)

    G2_GLOAD(0, 0);
    G2_LOADB(0);
    G2_STOREB();
    WAIT_ALL(); BAR();

    int cur = 0;
    for (int ks = 0; ks < K2_STEPS; ++ks) {   // 22
        const bool pf = (ks + 1 < K2_STEPS);
        if (pf) { G2_GLOAD(ks + 1, cur ^ 1); G2_LOADB(ks + 1); }
        G2_COMPUTE(cur);
        SCHED_FENCE();
        BAR();
        if (pf) G2_STOREB();
        WAIT_ALL(); BAR();
        cur ^= 1;
    }
#undef G2_GLOAD
#undef G2_LOADB
#undef G2_STOREB
#undef G2_COMPUTE

    float* yb = ybuf + (size_t)kb * ((size_t)MAXROWS * H_DIM);
    #pragma unroll
    for (int mi = 0; mi < 2; ++mi) {
        const f32x16 a = mi == 0 ? acc0 : acc1;
        #pragma unroll
        for (int r = 0; r < 16; ++r) {
            const int frow = wm * 64 + mi * 32 + (r & 3) + 8 * (r >> 2) + 4 * half;
            yb[(size_t)(opad + mt * 128 + frow) * H_DIM + it * 64 + wn * 32 + l31] = a[r];
        }
    }
}

// ---------------- combine ----------------
__global__ void combine_kernel(const float* __restrict__ ybuf,
                               const int4* __restrict__ comb,
                               float* __restrict__ out) {
    const int t = blockIdx.x;
    const int c = threadIdx.x;
    const int4 cb = comb[t];
    const float g0 = __int_as_float(cb.z), g1 = __int_as_float(cb.w);
    const size_t sp = (size_t)MAXROWS * H_DIM;
    const float4 a = ((const float4*)(ybuf + (size_t)cb.x * H_DIM))[c];
    const float4 b = ((const float4*)(ybuf + sp + (size_t)cb.x * H_DIM))[c];
    const float4 d = ((const float4*)(ybuf + (size_t)cb.y * H_DIM))[c];
    const float4 f = ((const float4*)(ybuf + sp + (size_t)cb.y * H_DIM))[c];
    float4 o;
    o.x = g0 * (a.x + b.x) + g1 * (d.x + f.x);
    o.y = g0 * (a.y + b.y) + g1 * (d.y + f.y);
    o.z = g0 * (a.z + b.z) + g1 * (d.z + f.z);
    o.w = g0 * (a.w + b.w) + g1 * (d.w + f.w);
    ((float4*)(out + (size_t)t * H_DIM))[c] = o;
}

extern "C" void kernel_launch(void* const* d_in, const int* in_sizes, int n_in,
                              void* d_out, int out_size, void* d_ws, size_t ws_size,
                              hipStream_t stream) {
    const float* x      = (const float*)d_in[0];
    const float* logits = (const float*)d_in[1];
    const float* w1     = (const float*)d_in[2];
    const float* w3     = (const float*)d_in[3];
    const float* w2     = (const float*)d_in[4];
    float* out = (float*)d_out;

    char* ws = (char*)d_ws;
    int*   tok  = (int*)ws;                                   // 8*1024 ints (32 KB)
    Meta*  meta = (Meta*)(ws + 65536);
    int4*  comb = (int4*)(ws + 69632);                        // 1024 * 16 B
    unsigned short* xb  = (unsigned short*)(ws + 131072);     // 1M bf16 (2 MB)
    unsigned short* act = (unsigned short*)(ws + 2228224);    // 3072 x 2816 bf16 (17.3 MB)
    float* ybuf = (float*)(ws + 19529728);                    // 2 x 3072 x 1024 fp32 (25.2 MB)

    route_kernel<<<1, 1024, 0, stream>>>(logits, tok, comb, meta);
    cvt_x_kernel<<<T_TOK * H_DIM / 4 / 256, 256, 0, stream>>>(x, xb);
    gemm1_kernel<<<dim3(8, E_NUM, I_DIM / 64), 256, 0, stream>>>(xb, w1, w3, tok, meta, act);
    gemm2_kernel<<<dim3(8 * KSPLIT, E_NUM, H_DIM / 64), 256, 0, stream>>>(act, w2, meta, ybuf);
    combine_kernel<<<T_TOK, 256, 0, stream>>>(ybuf, comb, out);
}

// Round 4
// 323.679 us; speedup vs baseline: 1.9536x; 1.9536x over previous
//
#include <hip/hip_runtime.h>
#include <stdint.h>

#define T_TOK 1024
#define H_DIM 1024
#define I_DIM 2816
#define E_NUM 8
#define KSPLIT 2
#define K2_STEPS (I_DIM / 64 / KSPLIT)   // 22 K-steps of 64 per split
#define MAXROWS 3072                     // worst case: 8 + 2048/128 = 24 tiles * 128

typedef __attribute__((ext_vector_type(8))) short bf16x8;
typedef __attribute__((ext_vector_type(4))) float f32x4;

struct Meta { int counts[E_NUM]; int tiles[E_NUM]; int offs[E_NUM]; };

__device__ __forceinline__ unsigned short f2b(float f) {
    unsigned u = __float_as_uint(f);
    u += 0x7fffu + ((u >> 16) & 1u);   // round-to-nearest-even
    return (unsigned short)(u >> 16);
}

__device__ __forceinline__ uint4 pack8(const float4 a, const float4 b) {
    union { unsigned short us[8]; uint4 v; } u;
    u.us[0] = f2b(a.x); u.us[1] = f2b(a.y); u.us[2] = f2b(a.z); u.us[3] = f2b(a.w);
    u.us[4] = f2b(b.x); u.us[5] = f2b(b.y); u.us[6] = f2b(b.z); u.us[7] = f2b(b.w);
    return u.v;
}

// ---------------- routing: softmax -> top2 -> renorm -> grouped token lists ----------------
__global__ void route_kernel(const float* __restrict__ logits,
                             int* __restrict__ tok,
                             int4* __restrict__ comb,
                             Meta* __restrict__ meta) {
    __shared__ int cnt[E_NUM];
    __shared__ int soffs[E_NUM];
    const int tid = threadIdx.x;   // == token id, blockDim=1024
    if (tid < E_NUM) cnt[tid] = 0;
    for (int j = tid; j < E_NUM * T_TOK; j += 1024) tok[j] = 0;
    __syncthreads();

    float p[E_NUM];
    const float* lrow = logits + tid * E_NUM;
    float m = -1e30f;
    #pragma unroll
    for (int e = 0; e < E_NUM; ++e) { p[e] = lrow[e]; m = fmaxf(m, p[e]); }
    #pragma unroll
    for (int e = 0; e < E_NUM; ++e) p[e] = __expf(p[e] - m);
    int e0 = 0; float v0 = p[0];
    #pragma unroll
    for (int e = 1; e < E_NUM; ++e) if (p[e] > v0) { v0 = p[e]; e0 = e; }
    int e1 = -1; float v1 = -1.f;
    #pragma unroll
    for (int e = 0; e < E_NUM; ++e) if (e != e0 && p[e] > v1) { v1 = p[e]; e1 = e; }
    const float inv = 1.f / (v0 + v1);       // softmax denom cancels in ratio
    const float g0 = v0 * inv, g1 = v1 * inv;

    const int p0 = atomicAdd(&cnt[e0], 1);
    const int p1 = atomicAdd(&cnt[e1], 1);
    tok[e0 * T_TOK + p0] = tid;
    tok[e1 * T_TOK + p1] = tid;
    __syncthreads();
    if (tid == 0) {
        int off = 0;
        for (int e = 0; e < E_NUM; ++e) {
            const int c = cnt[e];
            const int t = (c + 127) >> 7;
            meta->counts[e] = c; meta->tiles[e] = t; meta->offs[e] = off;
            soffs[e] = off;
            off += t * 128;
        }
    }
    __syncthreads();
    // padded row indices of this token's two expert slots + gates
    comb[tid] = make_int4(soffs[e0] + p0, soffs[e1] + p1,
                          __float_as_int(g0), __float_as_int(g1));
}

// ---------------- x fp32 -> bf16 ----------------
__global__ void cvt_x_kernel(const float* __restrict__ x, unsigned short* __restrict__ xb) {
    const int i = blockIdx.x * blockDim.x + threadIdx.x;
    const float4 v = ((const float4*)x)[i];
    ushort4 o; o.x = f2b(v.x); o.y = f2b(v.y); o.z = f2b(v.z); o.w = f2b(v.w);
    ((ushort4*)xb)[i] = o;
}

// ---------------- GEMM1: act = silu(x@w1^T) * (x@w3^T), grouped per expert ----------------
// grid: (I/64, E, maxMTiles), block 512 (8 waves). Tile: 128 tokens x 64 I-cols, BK=64.
// Single-buffer LDS + __syncthreads + 1-deep register prefetch (R1-proven, 93 us).
// LDS tiles XOR-swizzled: ushort col ^= (row&7)<<3.
__launch_bounds__(512)
__global__ void gemm1_kernel(const unsigned short* __restrict__ xb,
                             const float* __restrict__ w1,
                             const float* __restrict__ w3,
                             const int* __restrict__ tok,
                             const Meta* __restrict__ meta,
                             unsigned short* __restrict__ act) {
    const int e = blockIdx.y;
    const int mt = blockIdx.z;
    if (mt >= meta->tiles[e]) return;
    const int it = blockIdx.x;
    const int tid = threadIdx.x;

    __shared__ __align__(16) unsigned short As[128 * 64];   // 16 KB
    __shared__ __align__(16) unsigned short B1s[64 * 64];   // 8 KB
    __shared__ __align__(16) unsigned short B3s[64 * 64];   // 8 KB

    // ---- staging assignment: row = tid>>3 (0..63), 8-elem chunk = tid&7 ----
    const int srow = tid >> 3, ssub = tid & 7;
    const int t0 = tok[e * T_TOK + mt * 128 + srow];
    const int t1 = tok[e * T_TOK + mt * 128 + 64 + srow];
    const unsigned short* ap0 = xb + (size_t)t0 * H_DIM + ssub * 8;
    const unsigned short* ap1 = xb + (size_t)t1 * H_DIM + ssub * 8;
    const int scol = (ssub * 8) ^ ((srow & 7) << 3);
    unsigned short* al0 = &As[srow * 64 + scol];
    unsigned short* al1 = &As[(64 + srow) * 64 + scol];   // (64+srow)&7 == srow&7

    const size_t wbase = (size_t)e * I_DIM * H_DIM + (size_t)(it * 64 + srow) * H_DIM + ssub * 8;
    const float* b1p = w1 + wbase;
    const float* b3p = w3 + wbase;
    unsigned short* bl1 = &B1s[srow * 64 + scol];
    unsigned short* bl3 = &B3s[srow * 64 + scol];

    // ---- wave decomposition: 8 waves = 4(M) x 2(N), each 32x32 output ----
    const int wave = tid >> 6, lane = tid & 63;
    const int quad = lane >> 4, l15 = lane & 15;
    const int mbase = (wave >> 1) * 32;
    const int nbase = (wave & 1) * 32;

    f32x4 acc1[2][2], acc3[2][2];
    #pragma unroll
    for (int m = 0; m < 2; ++m)
        #pragma unroll
        for (int n = 0; n < 2; ++n) {
            acc1[m][n] = (f32x4){0.f, 0.f, 0.f, 0.f};
            acc3[m][n] = (f32x4){0.f, 0.f, 0.f, 0.f};
        }

    // register-1-deep-buffered staging
    uint4 ra0 = *(const uint4*)ap0, ra1 = *(const uint4*)ap1;
    float4 rb1a = *(const float4*)b1p, rb1b = *(const float4*)(b1p + 4);
    float4 rb3a = *(const float4*)b3p, rb3b = *(const float4*)(b3p + 4);

    const int NK = H_DIM / 64;   // 16
    for (int ks = 0; ks < NK; ++ks) {
        __syncthreads();
        *(uint4*)al0 = ra0;
        *(uint4*)al1 = ra1;
        *(uint4*)bl1 = pack8(rb1a, rb1b);
        *(uint4*)bl3 = pack8(rb3a, rb3b);
        __syncthreads();
        if (ks + 1 < NK) {
            const int k0 = (ks + 1) * 64;
            ra0 = *(const uint4*)(ap0 + k0);  ra1 = *(const uint4*)(ap1 + k0);
            rb1a = *(const float4*)(b1p + k0); rb1b = *(const float4*)(b1p + k0 + 4);
            rb3a = *(const float4*)(b3p + k0); rb3b = *(const float4*)(b3p + k0 + 4);
        }
        bf16x8 a[2][2], bf1[2][2], bf3[2][2];
        #pragma unroll
        for (int m = 0; m < 2; ++m) {
            const int row = mbase + m * 16 + l15;
            #pragma unroll
            for (int kk = 0; kk < 2; ++kk)
                a[m][kk] = *(const bf16x8*)&As[row * 64 + ((kk * 32 + quad * 8) ^ ((row & 7) << 3))];
        }
        #pragma unroll
        for (int n = 0; n < 2; ++n) {
            const int row = nbase + n * 16 + l15;
            #pragma unroll
            for (int kk = 0; kk < 2; ++kk) {
                const int off = row * 64 + ((kk * 32 + quad * 8) ^ ((row & 7) << 3));
                bf1[n][kk] = *(const bf16x8*)&B1s[off];
                bf3[n][kk] = *(const bf16x8*)&B3s[off];
            }
        }
        #pragma unroll
        for (int m = 0; m < 2; ++m)
            #pragma unroll
            for (int n = 0; n < 2; ++n)
                #pragma unroll
                for (int kk = 0; kk < 2; ++kk) {
                    acc1[m][n] = __builtin_amdgcn_mfma_f32_16x16x32_bf16(a[m][kk], bf1[n][kk], acc1[m][n], 0, 0, 0);
                    acc3[m][n] = __builtin_amdgcn_mfma_f32_16x16x32_bf16(a[m][kk], bf3[n][kk], acc3[m][n], 0, 0, 0);
                }
    }

    // epilogue: silu(h1)*h3 -> act (bf16). C/D layout: row=quad*4+reg, col=lane&15 (m89-verified)
    const int opad = meta->offs[e];
    #pragma unroll
    for (int m = 0; m < 2; ++m)
        #pragma unroll
        for (int n = 0; n < 2; ++n)
            #pragma unroll
            for (int rr = 0; rr < 4; ++rr) {
                const float v1 = acc1[m][n][rr];
                const float v3 = acc3[m][n][rr];
                const float s = v1 / (1.f + __expf(-v1)) * v3;
                const int row = opad + mt * 128 + mbase + m * 16 + quad * 4 + rr;
                const int col = it * 64 + nbase + n * 16 + l15;
                act[(size_t)row * I_DIM + col] = f2b(s);
            }
}

// ---------------- GEMM2: ybuf[kb] = act @ w2^T (K-split halves), plain stores ----------------
// Same proven loop structure as gemm1: 512 thr, tile 128x64, BK=64, single-buffer LDS.
// grid: (H/64, E, maxMTiles*KSPLIT). No atomics: partials -> ybuf, combined later.
__launch_bounds__(512)
__global__ void gemm2_kernel(const unsigned short* __restrict__ act,
                             const float* __restrict__ w2,
                             const Meta* __restrict__ meta,
                             float* __restrict__ ybuf) {
    const int e = blockIdx.y;
    const int mt = blockIdx.z >> 1;     // KSPLIT == 2
    const int kb = blockIdx.z & 1;
    if (mt >= meta->tiles[e]) return;
    const int it = blockIdx.x;
    const int tid = threadIdx.x;
    const int opad = meta->offs[e];
    const int kbase = kb * (K2_STEPS * 64);   // 0 or 1408

    __shared__ __align__(16) unsigned short As[128 * 64];   // 16 KB
    __shared__ __align__(16) unsigned short Bs[64 * 64];    // 8 KB

    const int srow = tid >> 3, ssub = tid & 7;
    const unsigned short* ap0 = act + (size_t)(opad + mt * 128 + srow) * I_DIM + kbase + ssub * 8;
    const unsigned short* ap1 = ap0 + (size_t)64 * I_DIM;
    const int scol = (ssub * 8) ^ ((srow & 7) << 3);
    unsigned short* al0 = &As[srow * 64 + scol];
    unsigned short* al1 = &As[(64 + srow) * 64 + scol];

    const float* bp = w2 + (size_t)e * H_DIM * I_DIM + (size_t)(it * 64 + srow) * I_DIM + kbase + ssub * 8;
    unsigned short* bl = &Bs[srow * 64 + scol];

    const int wave = tid >> 6, lane = tid & 63;
    const int quad = lane >> 4, l15 = lane & 15;
    const int mbase = (wave >> 1) * 32;
    const int nbase = (wave & 1) * 32;

    f32x4 acc[2][2];
    #pragma unroll
    for (int m = 0; m < 2; ++m)
        #pragma unroll
        for (int n = 0; n < 2; ++n) acc[m][n] = (f32x4){0.f, 0.f, 0.f, 0.f};

    uint4 ra0 = *(const uint4*)ap0, ra1 = *(const uint4*)ap1;
    float4 rba = *(const float4*)bp, rbb = *(const float4*)(bp + 4);

    for (int ks = 0; ks < K2_STEPS; ++ks) {   // 22
        __syncthreads();
        *(uint4*)al0 = ra0;
        *(uint4*)al1 = ra1;
        *(uint4*)bl = pack8(rba, rbb);
        __syncthreads();
        if (ks + 1 < K2_STEPS) {
            const int k0 = (ks + 1) * 64;
            ra0 = *(const uint4*)(ap0 + k0); ra1 = *(const uint4*)(ap1 + k0);
            rba = *(const float4*)(bp + k0); rbb = *(const float4*)(bp + k0 + 4);
        }
        bf16x8 a[2][2], bf[2][2];
        #pragma unroll
        for (int m = 0; m < 2; ++m) {
            const int row = mbase + m * 16 + l15;
            #pragma unroll
            for (int kk = 0; kk < 2; ++kk)
                a[m][kk] = *(const bf16x8*)&As[row * 64 + ((kk * 32 + quad * 8) ^ ((row & 7) << 3))];
        }
        #pragma unroll
        for (int n = 0; n < 2; ++n) {
            const int row = nbase + n * 16 + l15;
            #pragma unroll
            for (int kk = 0; kk < 2; ++kk)
                bf[n][kk] = *(const bf16x8*)&Bs[row * 64 + ((kk * 32 + quad * 8) ^ ((row & 7) << 3))];
        }
        #pragma unroll
        for (int m = 0; m < 2; ++m)
            #pragma unroll
            for (int n = 0; n < 2; ++n)
                #pragma unroll
                for (int kk = 0; kk < 2; ++kk)
                    acc[m][n] = __builtin_amdgcn_mfma_f32_16x16x32_bf16(a[m][kk], bf[n][kk], acc[m][n], 0, 0, 0);
    }

    // epilogue: plain stores of fp32 partials (no atomics); padded rows written harmlessly
    float* yb = ybuf + (size_t)kb * ((size_t)MAXROWS * H_DIM);
    #pragma unroll
    for (int m = 0; m < 2; ++m)
        #pragma unroll
        for (int rr = 0; rr < 4; ++rr) {
            const int grow = opad + mt * 128 + mbase + m * 16 + quad * 4 + rr;
            #pragma unroll
            for (int n = 0; n < 2; ++n) {
                const int col = it * 64 + nbase + n * 16 + l15;
                yb[(size_t)grow * H_DIM + col] = acc[m][n][rr];
            }
        }
}

// ---------------- combine: out[t] = g0*(y[0][r0]+y[1][r0]) + g1*(y[0][r1]+y[1][r1]) ----------------
__global__ void combine_kernel(const float* __restrict__ ybuf,
                               const int4* __restrict__ comb,
                               float* __restrict__ out) {
    const int t = blockIdx.x;
    const int c = threadIdx.x;            // float4 column group, 256 per row
    const int4 cb = comb[t];
    const float g0 = __int_as_float(cb.z), g1 = __int_as_float(cb.w);
    const size_t sp = (size_t)MAXROWS * H_DIM;
    const float4 a = ((const float4*)(ybuf + (size_t)cb.x * H_DIM))[c];
    const float4 b = ((const float4*)(ybuf + sp + (size_t)cb.x * H_DIM))[c];
    const float4 d = ((const float4*)(ybuf + (size_t)cb.y * H_DIM))[c];
    const float4 f = ((const float4*)(ybuf + sp + (size_t)cb.y * H_DIM))[c];
    float4 o;
    o.x = g0 * (a.x + b.x) + g1 * (d.x + f.x);
    o.y = g0 * (a.y + b.y) + g1 * (d.y + f.y);
    o.z = g0 * (a.z + b.z) + g1 * (d.z + f.z);
    o.w = g0 * (a.w + b.w) + g1 * (d.w + f.w);
    ((float4*)(out + (size_t)t * H_DIM))[c] = o;
}

extern "C" void kernel_launch(void* const* d_in, const int* in_sizes, int n_in,
                              void* d_out, int out_size, void* d_ws, size_t ws_size,
                              hipStream_t stream) {
    const float* x      = (const float*)d_in[0];
    const float* logits = (const float*)d_in[1];
    const float* w1     = (const float*)d_in[2];
    const float* w3     = (const float*)d_in[3];
    const float* w2     = (const float*)d_in[4];
    float* out = (float*)d_out;

    char* ws = (char*)d_ws;
    int*   tok  = (int*)ws;                                   // 8*1024 ints (32 KB)
    Meta*  meta = (Meta*)(ws + 65536);
    int4*  comb = (int4*)(ws + 69632);                        // 1024 * 16 B
    unsigned short* xb  = (unsigned short*)(ws + 131072);     // 1M bf16 (2 MB)
    unsigned short* act = (unsigned short*)(ws + 2228224);    // 3072 x 2816 bf16 (17.3 MB)
    float* ybuf = (float*)(ws + 19529728);                    // 2 x 3072 x 1024 fp32 (25.2 MB)

    route_kernel<<<1, 1024, 0, stream>>>(logits, tok, comb, meta);
    cvt_x_kernel<<<T_TOK * H_DIM / 4 / 256, 256, 0, stream>>>(x, xb);
    gemm1_kernel<<<dim3(I_DIM / 64, E_NUM, 8), 512, 0, stream>>>(xb, w1, w3, tok, meta, act);
    gemm2_kernel<<<dim3(H_DIM / 64, E_NUM, 8 * KSPLIT), 512, 0, stream>>>(act, w2, meta, ybuf);
    combine_kernel<<<T_TOK, 256, 0, stream>>>(ybuf, comb, out);
}